// Round 4
// baseline (1467.429 us; speedup 1.0000x reference)
//
#include <hip/hip_runtime.h>
#include <hip/hip_bf16.h>
#include <cmath>

// ---------------------------------------------------------------------------
// FourierNet fused forward, MI355X / gfx950.
// Round 4: arithmetic-intensity attack.
//  - TM=128 pts/block (512 blocks): halves global weight demand.
//  - 8 waves = (2 point-halves) x (4 H-quarters); wave tile = 64pts x 64H:
//    per K-step 4 wfrag + 4 afrag + 16 MFMA (weight frag reused 4x,
//    LDS bytes/MFMA = 0.25KB -> under the 256B/cy/CU LDS ceiling).
//  - bf16 weights packed K-step-tiled [kstep][256][32] in d_ws -> coalesced
//    1KB dense wfrag loads; proj K freq-interleaved (k' = j*8+g) so fourier
//    writes are contiguous b128 and proj runs as 2 K=256 chunks.
//  - LDS 139.3KB (1 block/CU), launch_bounds(512,2) -> 256 VGPR budget.
// ---------------------------------------------------------------------------

#define NSC   4
#define NFREQ 64
#define HID   256
#define NBLK  2
#define INF   514
#define TM    128
#define HSTR  264            // row stride (elems) for f-chunk/h/t tiles
#define NTHR  512

// LDS byte offsets
#define BUF0_OFF 0                      // f chunk0 / h   (128 x 264 bf16)
#define BUF1_OFF 67584                  // f chunk1 / t
#define XYX_OFF  135168
#define XYY_OFF  135680
#define BXY_OFF  136192
#define SCF_OFF  136704
#define OUTL_OFF 138752
#define SMEM_BYTES 139264

// d_ws packed-weight layout (bf16 elems): tiles of [256 rows][32 k]
#define TILE_E   8192                       // 256*32
#define PROJ_OFF(s)    ((s) * 131072)       // 16 tiles per scale (K=512)
#define W1_OFF   524288                     // 8 matrices x 8 tiles
#define W2_OFF   1048576
#define WSB_ELEMS 1572864

static constexpr float S_IN = 0.04411042041035620f;  // 1/sqrt(514)
static constexpr float S_H  = 0.0625f;               // 1/sqrt(256)

typedef __attribute__((ext_vector_type(8))) short bf16x8;
typedef __attribute__((ext_vector_type(4))) float f32x4;

__device__ __forceinline__ unsigned short f2bf(float v) {
  __hip_bfloat16 b = __float2bfloat16(v);   // RNE
  unsigned short u;
  __builtin_memcpy(&u, &b, 2);
  return u;
}

__device__ __forceinline__ unsigned pack2(float a, float b) {
  return (unsigned)f2bf(a) | ((unsigned)f2bf(b) << 16);
}

__device__ __forceinline__ float geluf(float x) {
  return 0.5f * x * (1.0f + erff(x * 0.7071067811865476f));
}

// ---------------------------------------------------------------------------
// Packed-weight GEMM over one K=256 span (8 K-steps).
//   W frag (1st op): row = hq*64 + hf*16 + (lane&15), k = ks*32 + 8*(lane>>4)
//   A frag (2nd op, LDS): point = ph*64 + pf*16 + (lane&15), same k
//   D: point-col = lane&15 (+16pf+64ph), H-row = hq*64+hf*16+4*(lane>>4)+r
// 2-deep weight prefetch; fully unrolled.
// PERM: fp32 fallback uses freq-interleaved proj column mapping.
// ---------------------------------------------------------------------------
template<bool WS, bool PERM>
__device__ __forceinline__ void gemm8(const unsigned short* a_base,
                                      const unsigned short* __restrict__ wt,
                                      const float* __restrict__ wf,
                                      const int fp_rs, const int fp_co,
                                      const int fp_j0,
                                      const int lane, const int hq, const int ph,
                                      f32x4 acc[4][4]) {
  const int ar = lane & 15;
  const int q  = lane >> 4;

  bf16x8 wb[2][4];
  auto loadw = [&](int ks, bf16x8 w[4]) {
#pragma unroll
    for (int hf = 0; hf < 4; ++hf) {
      const int row = hq * 64 + hf * 16 + ar;
      if constexpr (WS) {
        w[hf] = *(const bf16x8*)(wt + ks * TILE_E + row * 32 + q * 8);
      } else if constexpr (PERM) {
        const int j = fp_j0 + ks * 4 + q;
        const float* p = wf + row * fp_rs + fp_co;
#pragma unroll
        for (int g = 0; g < 8; ++g) w[hf][g] = (short)f2bf(p[g * 64 + j]);
      } else {
        const float* p = wf + row * fp_rs + fp_co + ks * 32 + q * 8;
#pragma unroll
        for (int g = 0; g < 8; ++g) w[hf][g] = (short)f2bf(p[g]);
      }
    }
  };

  loadw(0, wb[0]);
  loadw(1, wb[1]);
#pragma unroll
  for (int ks = 0; ks < 8; ++ks) {
    bf16x8 a[4];
#pragma unroll
    for (int pf = 0; pf < 4; ++pf)
      a[pf] = *(const bf16x8*)(a_base + (ph * 64 + pf * 16 + ar) * HSTR + ks * 32 + q * 8);
#pragma unroll
    for (int hf = 0; hf < 4; ++hf)
#pragma unroll
      for (int pf = 0; pf < 4; ++pf)
        acc[hf][pf] = __builtin_amdgcn_mfma_f32_16x16x32_bf16(wb[ks & 1][hf], a[pf],
                                                              acc[hf][pf], 0, 0, 0);
    if (ks + 2 < 8) loadw(ks + 2, wb[ks & 1]);
  }
}

// ---------------------------------------------------------------------------
// Weight pre-pack: fp32 -> bf16, K-step-tiled [kstep][256][32]; proj columns
// additionally permuted to k' = j*8 + g (freq-major interleave).
// dst linear index == i by construction.
// ---------------------------------------------------------------------------
__global__ void cvt_weights(const float* __restrict__ projW,
                            const float* __restrict__ w1,
                            const float* __restrict__ w2,
                            unsigned short* __restrict__ o) {
  const int tot = WSB_ELEMS;
  for (int i = blockIdx.x * blockDim.x + threadIdx.x; i < tot;
       i += gridDim.x * blockDim.x) {
    float v;
    if (i < W1_OFF) {
      const int s = i >> 17, r = i & 131071;
      const int kst = r >> 13, rr = r & 8191;
      const int h = rr >> 5, kw = rr & 31;
      const int kp = kst * 32 + kw;            // permuted k'
      const int j = kp >> 3, g = kp & 7;
      v = projW[(s * HID + h) * INF + 2 + g * 64 + j];
    } else if (i < W2_OFF) {
      const int i2 = i - W1_OFF;
      const int w = i2 >> 16, r = i2 & 65535;
      const int kst = r >> 13, h = (r >> 5) & 255, kw = r & 31;
      v = w1[w * 65536 + h * HID + kst * 32 + kw];
    } else {
      const int i2 = i - W2_OFF;
      const int w = i2 >> 16, r = i2 & 65535;
      const int kst = r >> 13, h = (r >> 5) & 255, kw = r & 31;
      v = w2[w * 65536 + h * HID + kst * 32 + kw];
    }
    o[i] = f2bf(v);
  }
}

template<bool WS>
__global__ __launch_bounds__(NTHR, 2)
void fnet_fused(const float* __restrict__ xy,
                const float* __restrict__ w_x,
                const float* __restrict__ w_y,
                const float* __restrict__ proj_W,
                const float* __restrict__ proj_b,
                const float* __restrict__ blk_W1,
                const float* __restrict__ blk_b1,
                const float* __restrict__ blk_W2,
                const float* __restrict__ blk_b2,
                const float* __restrict__ head_W,
                const float* __restrict__ head_b,
                const float* __restrict__ sc_W,
                const unsigned short* __restrict__ wsb,
                float* __restrict__ out) {
  extern __shared__ char smem[];
  unsigned short* buf0 = (unsigned short*)(smem + BUF0_OFF);  // f c0 / h
  unsigned short* buf1 = (unsigned short*)(smem + BUF1_OFF);  // f c1 / t
  float* xyx  = (float*)(smem + XYX_OFF);
  float* xyy  = (float*)(smem + XYY_OFF);
  float* Bxy  = (float*)(smem + BXY_OFF);    // Bx[64] | By[64]
  float* scf  = (float*)(smem + SCF_OFF);    // 512 shortcut weights
  float* outl = (float*)(smem + OUTL_OFF);   // 128 output accumulators

  const int tid  = threadIdx.x;
  const int lane = tid & 63;
  const int wave = tid >> 6;           // 0..7
  const int ph   = wave & 1;           // point half (64 pts)
  const int hq   = wave >> 1;          // H quarter (64 H)
  const int m0   = blockIdx.x * TM;
  const int ar   = lane & 15;
  const int q    = lane >> 4;

  if (tid < TM) {
    xyx[tid] = xy[(m0 + tid) * 2];
    xyy[tid] = xy[(m0 + tid) * 2 + 1];
    outl[tid] = 0.f;
  }

  // head weights for this lane's 16 H slots
  float hw[4][4];
#pragma unroll
  for (int hf = 0; hf < 4; ++hf) {
    const float4 h4 = *(const float4*)(head_W + hq * 64 + hf * 16 + 4 * q);
    hw[hf][0] = h4.x; hw[hf][1] = h4.y; hw[hf][2] = h4.z; hw[hf][3] = h4.w;
  }

  const int fm = tid >> 2;   // fourier point (0..127)
  const int fq = tid & 3;    // freq quarter within chunk
  float psc = 0.f;

  for (int s = 0; s < NSC; ++s) {
    __syncthreads();   // prior-scale LDS uses complete
    if (tid < NFREQ)          Bxy[tid] = expf(w_x[s * NFREQ + tid]);
    else if (tid < 2 * NFREQ) Bxy[tid] = expf(w_y[s * NFREQ + tid - NFREQ]);
    scf[tid] = sc_W[s * INF + 2 + tid];
    __syncthreads();

    // ---- fourier chunk generator: 32 freqs -> fbuf[pt][jl*8+g] ----
    auto fourier_chunk = [&](int c, unsigned short* fbuf) {
      const float x = xyx[fm], yv = xyy[fm];
      if (fq == 0 && c == 0) psc += x * sc_W[s * INF] + yv * sc_W[s * INF + 1];
#pragma unroll
      for (int i = 0; i < 8; ++i) {
        const int jl = fq * 8 + i;          // 0..31
        const int jg = c * 32 + jl;         // 0..63
        const float bx = Bxy[jg], by = Bxy[NFREQ + jg];
        float tx = 0.5f * x * bx;  tx -= floorf(tx);
        float ty = 0.5f * yv * by; ty -= floorf(ty);
        const float sx = __builtin_amdgcn_sinf(tx);
        const float cx = __builtin_amdgcn_cosf(tx);
        const float sy = __builtin_amdgcn_sinf(ty);
        const float cy = __builtin_amdgcn_cosf(ty);
        const float p1 = sx * cy, p2 = cx * sy, p3 = cx * cy, p4 = sx * sy;
        const float g0 = sx, g1 = cx, g2 = sy, g3 = cy;
        const float g4 = p1 + p2, g5 = p3 - p4, g6 = p1 - p2, g7 = p3 + p4;
        uint4 wv;
        wv.x = pack2(g0, g1); wv.y = pack2(g2, g3);
        wv.z = pack2(g4, g5); wv.w = pack2(g6, g7);
        *(uint4*)((char*)fbuf + fm * (HSTR * 2) + jl * 16) = wv;
        psc += g0 * scf[jg]            + g1 * scf[NFREQ + jg]
             + g2 * scf[2 * NFREQ + jg] + g3 * scf[3 * NFREQ + jg]
             + g4 * scf[4 * NFREQ + jg] + g5 * scf[5 * NFREQ + jg]
             + g6 * scf[6 * NFREQ + jg] + g7 * scf[7 * NFREQ + jg];
      }
    };

    fourier_chunk(0, buf0);
    __syncthreads();

    // ---- proj GEMM chunk 0 (+ fourier chunk 1 overlapped across waves) ----
    f32x4 acc[4][4];
#pragma unroll
    for (int a_ = 0; a_ < 4; ++a_)
#pragma unroll
      for (int b_ = 0; b_ < 4; ++b_) acc[a_][b_] = (f32x4)0.f;

    gemm8<WS, true>(buf0, wsb + PROJ_OFF(s),
                    proj_W + s * HID * INF, INF, 2, 0, lane, hq, ph, acc);
    fourier_chunk(1, buf1);
    __syncthreads();

    gemm8<WS, true>(buf1, wsb + PROJ_OFF(s) + 8 * TILE_E,
                    proj_W + s * HID * INF, INF, 2, 32, lane, hq, ph, acc);

    // ---- proj epilogue -> hres ----
    float xp[4], yp[4];
#pragma unroll
    for (int pf = 0; pf < 4; ++pf) {
      xp[pf] = xyx[ph * 64 + pf * 16 + ar];
      yp[pf] = xyy[ph * 64 + pf * 16 + ar];
    }
    f32x4 hres[4][4];
#pragma unroll
    for (int hf = 0; hf < 4; ++hf) {
      const int Hb = hq * 64 + hf * 16 + 4 * q;
      const float4 pb4 = *(const float4*)(proj_b + s * HID + Hb);
      const float pbv[4] = {pb4.x, pb4.y, pb4.z, pb4.w};
      float wx0[4], wy0[4];
#pragma unroll
      for (int r = 0; r < 4; ++r) {
        const float2 w01 = *(const float2*)(proj_W + (size_t)(s * HID + Hb + r) * INF);
        wx0[r] = w01.x; wy0[r] = w01.y;
      }
#pragma unroll
      for (int pf = 0; pf < 4; ++pf)
#pragma unroll
        for (int r = 0; r < 4; ++r)
          hres[hf][pf][r] = geluf((acc[hf][pf][r] + xp[pf] * wx0[r] + yp[pf] * wy0[r])
                                      * S_IN + pbv[r]);
    }
    __syncthreads();   // all waves done reading buf0/buf1 as fourier chunks

    auto store_tile = [&](unsigned short* dst, const f32x4 v[4][4]) {
#pragma unroll
      for (int hf = 0; hf < 4; ++hf) {
        const int Hb = hq * 64 + hf * 16 + 4 * q;
#pragma unroll
        for (int pf = 0; pf < 4; ++pf)
          *(uint2*)(dst + (ph * 64 + pf * 16 + ar) * HSTR + Hb) =
              make_uint2(pack2(v[hf][pf][0], v[hf][pf][1]),
                         pack2(v[hf][pf][2], v[hf][pf][3]));
      }
    };
    store_tile(buf0, hres);   // h -> buf0
    __syncthreads();

    // ---- residual blocks ----
    for (int b = 0; b < NBLK; ++b) {
      const int wb_ = s * NBLK + b;
      f32x4 acc2[4][4];
#pragma unroll
      for (int a_ = 0; a_ < 4; ++a_)
#pragma unroll
        for (int b_ = 0; b_ < 4; ++b_) acc2[a_][b_] = (f32x4)0.f;
      gemm8<WS, false>(buf0, wsb + W1_OFF + wb_ * 65536,
                       blk_W1 + wb_ * 65536, HID, 0, 0, lane, hq, ph, acc2);
      // t = gelu(acc2*s_h + b1) -> buf1 (all waves past chunk-1/prev-b reads)
      f32x4 tres[4][4];
#pragma unroll
      for (int hf = 0; hf < 4; ++hf) {
        const int Hb = hq * 64 + hf * 16 + 4 * q;
        const float4 b14 = *(const float4*)(blk_b1 + wb_ * HID + Hb);
        const float b1v[4] = {b14.x, b14.y, b14.z, b14.w};
#pragma unroll
        for (int pf = 0; pf < 4; ++pf)
#pragma unroll
          for (int r = 0; r < 4; ++r)
            tres[hf][pf][r] = geluf(acc2[hf][pf][r] * S_H + b1v[r]);
      }
      store_tile(buf1, tres);
      __syncthreads();   // t complete, all h reads done

      f32x4 acc3[4][4];
#pragma unroll
      for (int a_ = 0; a_ < 4; ++a_)
#pragma unroll
        for (int b_ = 0; b_ < 4; ++b_) acc3[a_][b_] = (f32x4)0.f;
      gemm8<WS, false>(buf1, wsb + W2_OFF + wb_ * 65536,
                       blk_W2 + wb_ * 65536, HID, 0, 0, lane, hq, ph, acc3);
#pragma unroll
      for (int hf = 0; hf < 4; ++hf) {
        const int Hb = hq * 64 + hf * 16 + 4 * q;
        const float4 b24 = *(const float4*)(blk_b2 + wb_ * HID + Hb);
        const float b2v[4] = {b24.x, b24.y, b24.z, b24.w};
#pragma unroll
        for (int pf = 0; pf < 4; ++pf)
#pragma unroll
          for (int r = 0; r < 4; ++r)
            hres[hf][pf][r] += acc3[hf][pf][r] * S_H + b2v[r];
      }
      if (b + 1 < NBLK) store_tile(buf0, hres);  // safe: gemm1 readers all past barrier
      __syncthreads();
    }

    // ---- head partial ----
#pragma unroll
    for (int pf = 0; pf < 4; ++pf) {
      float v = 0.f;
#pragma unroll
      for (int hf = 0; hf < 4; ++hf)
#pragma unroll
        for (int r = 0; r < 4; ++r) v += hres[hf][pf][r] * hw[hf][r];
      v += __shfl_xor(v, 16, 64);
      v += __shfl_xor(v, 32, 64);
      if (lane < 16) atomicAdd(&outl[ph * 64 + pf * 16 + ar], v);
    }
  }

  // ---- shortcut reduce (4 threads per point) + final write ----
  psc += __shfl_xor(psc, 1, 64);
  psc += __shfl_xor(psc, 2, 64);
  if (fq == 0) atomicAdd(&outl[fm], psc);
  __syncthreads();
  if (tid < TM) out[m0 + tid] = outl[tid] + head_b[0];
}

extern "C" void kernel_launch(void* const* d_in, const int* in_sizes, int n_in,
                              void* d_out, int out_size, void* d_ws, size_t ws_size,
                              hipStream_t stream) {
  (void)in_sizes; (void)n_in;
  const float* xy     = (const float*)d_in[0];
  const float* w_x    = (const float*)d_in[1];
  const float* w_y    = (const float*)d_in[2];
  const float* proj_W = (const float*)d_in[3];
  const float* proj_b = (const float*)d_in[4];
  const float* blk_W1 = (const float*)d_in[5];
  const float* blk_b1 = (const float*)d_in[6];
  const float* blk_W2 = (const float*)d_in[7];
  const float* blk_b2 = (const float*)d_in[8];
  const float* head_W = (const float*)d_in[9];
  const float* head_b = (const float*)d_in[10];
  const float* sc_W   = (const float*)d_in[11];
  float* out = (float*)d_out;

  const bool use_ws = ws_size >= (size_t)WSB_ELEMS * 2;
  const int nblocks = out_size / TM;   // 65536/128 = 512

  if (use_ws) {
    hipFuncSetAttribute((const void*)fnet_fused<true>,
                        hipFuncAttributeMaxDynamicSharedMemorySize, SMEM_BYTES);
    cvt_weights<<<768, 256, 0, stream>>>(proj_W, blk_W1, blk_W2,
                                         (unsigned short*)d_ws);
    fnet_fused<true><<<nblocks, NTHR, SMEM_BYTES, stream>>>(
        xy, w_x, w_y, proj_W, proj_b, blk_W1, blk_b1, blk_W2, blk_b2,
        head_W, head_b, sc_W, (const unsigned short*)d_ws, out);
  } else {
    hipFuncSetAttribute((const void*)fnet_fused<false>,
                        hipFuncAttributeMaxDynamicSharedMemorySize, SMEM_BYTES);
    fnet_fused<false><<<nblocks, NTHR, SMEM_BYTES, stream>>>(
        xy, w_x, w_y, proj_W, proj_b, blk_W1, blk_b1, blk_W2, blk_b2,
        head_W, head_b, sc_W, (const unsigned short*)nullptr, out);
  }
}

// Round 5
// 873.484 us; speedup vs baseline: 1.6800x; 1.6800x over previous
//
#include <hip/hip_runtime.h>
#include <hip/hip_bf16.h>
#include <cmath>

// ---------------------------------------------------------------------------
// FourierNet fused forward, MI355X / gfx950.
// Round 5: occupancy + L2 design.
//  - TM=128, 1024 threads = 16 waves -> 4 waves/SIMD even at 1 block/CU.
//  - 16 waves = 4 pt-quarters x 4 H-quarters (wave tile 32pt x 64H):
//    per K-step 4 wfrag(global) + 2 afrag(LDS) + 8 MFMA.
//  - Full K=512 fourier tile in LDS, XOR-swizzled (slot ^ (pt&7)), NO pad:
//    131 KB arena; h (lower 64KB) and t (upper 64KB) alias it. 134.7 KB total.
//  - No persistent hres across res-blocks: residual base is read back from
//    LDS bf16 h -> VGPR <= 128 so 16 waves/CU actually fit (m69 VGPR steps).
//  - Fourier: thread = (pt-group, j): scf/exp in registers; each wave writes
//    full conflict-free 1KB LDS rows.
//  - Weight pre-pack in d_ws identical to R4 (verified): [kstep][256][32],
//    proj k' = j*8+g freq-interleave.
// ---------------------------------------------------------------------------

#define NSC   4
#define NFREQ 64
#define HID   256
#define NBLK  2
#define INF   514
#define TM    128
#define NTHR  1024

// LDS byte offsets
#define T_OFF    65536                  // t tile (upper half of f arena)
#define XYX_OFF  131072
#define XYY_OFF  131584
#define OUTL_OFF 132096
#define SMEM_BYTES 132608

// d_ws packed-weight layout (bf16 elems): tiles of [kstep][256 rows][32 k]
#define TILE_E   8192
#define PROJ_OFF(s)    ((s) * 131072)
#define W1_OFF   524288
#define W2_OFF   1048576
#define WSB_ELEMS 1572864

static constexpr float S_IN = 0.04411042041035620f;  // 1/sqrt(514)
static constexpr float S_H  = 0.0625f;               // 1/sqrt(256)

typedef __attribute__((ext_vector_type(8))) short bf16x8;
typedef __attribute__((ext_vector_type(4))) float f32x4;

__device__ __forceinline__ unsigned short f2bf(float v) {
  __hip_bfloat16 b = __float2bfloat16(v);   // RNE
  unsigned short u;
  __builtin_memcpy(&u, &b, 2);
  return u;
}

__device__ __forceinline__ unsigned pack2(float a, float b) {
  return (unsigned)f2bf(a) | ((unsigned)f2bf(b) << 16);
}

__device__ __forceinline__ float geluf(float x) {
  return 0.5f * x * (1.0f + erff(x * 0.7071067811865476f));
}

// ---------------------------------------------------------------------------
// GEMM over KSTEPS K-steps. A (activations) from swizzled LDS, W from global.
//   W frag: row = hq*64 + hf*16 + (lane&15), k = ks*32 + 8*(lane>>4)
//   A frag: pt  = ph*32 + pf*16 + (lane&15), same k; LDS slot16 swizzled by
//           slot' = (ks*4+q) ^ (pt&7) within a ROWB-byte row.
//   D: pt-col = lane&15, H-row = hq*64+hf*16+4*(lane>>4)+r   [m89]
// 1-ahead weight prefetch (load-to-use ~ one CU K-step ~620cy > L3 latency).
// ---------------------------------------------------------------------------
template<bool WS, bool PERM, int KSTEPS, int ROWB>
__device__ __forceinline__ void gemmK(const char* a_base,
                                      const unsigned short* __restrict__ wt,
                                      const float* __restrict__ wf,
                                      const int fp_rs, const int fp_co,
                                      const int lane, const int hq, const int ph,
                                      f32x4 acc[4][2]) {
  const int ar = lane & 15;
  const int q  = lane >> 4;
  bf16x8 wb[2][4];

  auto loadw = [&](int ks, bf16x8 w[4]) {
#pragma unroll
    for (int hf = 0; hf < 4; ++hf) {
      const int row = hq * 64 + hf * 16 + ar;
      if constexpr (WS) {
        w[hf] = *(const bf16x8*)(wt + ks * TILE_E + row * 32 + q * 8);
      } else if constexpr (PERM) {
        const int j = ks * 4 + q;
        const float* p = wf + row * fp_rs + fp_co;
#pragma unroll
        for (int e = 0; e < 8; ++e) w[hf][e] = (short)f2bf(p[e * 64 + j]);
      } else {
        const float* p = wf + row * fp_rs + fp_co + ks * 32 + q * 8;
#pragma unroll
        for (int e = 0; e < 8; ++e) w[hf][e] = (short)f2bf(p[e]);
      }
    }
  };

  loadw(0, wb[0]);
#pragma unroll
  for (int ks = 0; ks < KSTEPS; ++ks) {
    if (ks + 1 < KSTEPS) loadw(ks + 1, wb[(ks + 1) & 1]);
    bf16x8 a[2];
#pragma unroll
    for (int pf = 0; pf < 2; ++pf) {
      const int pt = ph * 32 + pf * 16 + ar;
      const int slot = (ks * 4 + q) ^ (pt & 7);
      a[pf] = *(const bf16x8*)(a_base + pt * ROWB + (slot << 4));
    }
#pragma unroll
    for (int hf = 0; hf < 4; ++hf)
#pragma unroll
      for (int pf = 0; pf < 2; ++pf)
        acc[hf][pf] = __builtin_amdgcn_mfma_f32_16x16x32_bf16(wb[ks & 1][hf], a[pf],
                                                              acc[hf][pf], 0, 0, 0);
  }
}

// Weight pre-pack (identical to R4, verified): [kstep][256][32] tiles,
// proj columns permuted k' = j*8+g (source col = 2 + g*64 + j).
__global__ void cvt_weights(const float* __restrict__ projW,
                            const float* __restrict__ w1,
                            const float* __restrict__ w2,
                            unsigned short* __restrict__ o) {
  const int tot = WSB_ELEMS;
  for (int i = blockIdx.x * blockDim.x + threadIdx.x; i < tot;
       i += gridDim.x * blockDim.x) {
    float v;
    if (i < W1_OFF) {
      const int s = i >> 17, r = i & 131071;
      const int kst = r >> 13, rr = r & 8191;
      const int h = rr >> 5, kw = rr & 31;
      const int kp = kst * 32 + kw;
      const int j = kp >> 3, g = kp & 7;
      v = projW[(s * HID + h) * INF + 2 + g * 64 + j];
    } else if (i < W2_OFF) {
      const int i2 = i - W1_OFF;
      const int w = i2 >> 16, r = i2 & 65535;
      const int kst = r >> 13, h = (r >> 5) & 255, kw = r & 31;
      v = w1[w * 65536 + h * HID + kst * 32 + kw];
    } else {
      const int i2 = i - W2_OFF;
      const int w = i2 >> 16, r = i2 & 65535;
      const int kst = r >> 13, h = (r >> 5) & 255, kw = r & 31;
      v = w2[w * 65536 + h * HID + kst * 32 + kw];
    }
    o[i] = f2bf(v);
  }
}

template<bool WS>
__global__ __launch_bounds__(NTHR, 4)
void fnet_fused(const float* __restrict__ xy,
                const float* __restrict__ w_x,
                const float* __restrict__ w_y,
                const float* __restrict__ proj_W,
                const float* __restrict__ proj_b,
                const float* __restrict__ blk_W1,
                const float* __restrict__ blk_b1,
                const float* __restrict__ blk_W2,
                const float* __restrict__ blk_b2,
                const float* __restrict__ head_W,
                const float* __restrict__ head_b,
                const float* __restrict__ sc_W,
                const unsigned short* __restrict__ wsb,
                float* __restrict__ out) {
  extern __shared__ char smem[];
  char* f_arena = smem;                  // 128 x 1024B swizzled (K=512 bf16)
  char* h_base  = smem;                  // 128 x 512B swizzled (aliases lower)
  char* t_base  = smem + T_OFF;          // 128 x 512B swizzled (aliases upper)
  float* xyx  = (float*)(smem + XYX_OFF);
  float* xyy  = (float*)(smem + XYY_OFF);
  float* outl = (float*)(smem + OUTL_OFF);

  const int tid  = threadIdx.x;
  const int lane = tid & 63;
  const int wave = tid >> 6;           // 0..15
  const int hq   = wave >> 2;          // H quarter (64 H)
  const int ph   = wave & 3;           // pt quarter (32 pts)
  const int m0   = blockIdx.x * TM;
  const int ar   = lane & 15;
  const int q    = lane >> 4;

  if (tid < TM) {
    xyx[tid] = xy[(m0 + tid) * 2];
    xyy[tid] = xy[(m0 + tid) * 2 + 1];
    outl[tid] = 0.f;
  }

  // head weights for this lane's 16 H slots
  float hw[4][4];
#pragma unroll
  for (int hf = 0; hf < 4; ++hf) {
    const float4 h4 = *(const float4*)(head_W + hq * 64 + hf * 16 + 4 * q);
    hw[hf][0] = h4.x; hw[hf][1] = h4.y; hw[hf][2] = h4.z; hw[hf][3] = h4.w;
  }

  // fourier mapping: one wave owns an 8-pt group; lane = freq j
  const int fj  = lane;        // 0..63
  const int ptg = wave;        // 0..15 -> pts ptg*8 .. +7
  float psc[8];
#pragma unroll
  for (int p = 0; p < 8; ++p) psc[p] = 0.f;

  // LDS store/readback helpers for h/t tiles (swizzled, ROWB=512)
  auto tile_addr = [&](char* base, int hf, int pf) -> char* {
    const int pt = ph * 32 + pf * 16 + ar;
    const int slot = (hq * 8 + hf * 2 + (q >> 1)) ^ (pt & 7);
    return base + pt * 512 + (slot << 4) + (q & 1) * 8;
  };

  for (int s = 0; s < NSC; ++s) {
    __syncthreads();   // prev-scale LDS reads (and xyx staging) complete

    // ---- fourier features -> f arena (swizzled b128 rows), shortcut dot ----
    {
      const float bx = expf(w_x[s * NFREQ + fj]);
      const float by = expf(w_y[s * NFREQ + fj]);
      float sc8[8];
#pragma unroll
      for (int g2 = 0; g2 < 8; ++g2) sc8[g2] = sc_W[s * INF + 2 + g2 * NFREQ + fj];
      const float scW0 = sc_W[s * INF], scW1 = sc_W[s * INF + 1];
#pragma unroll
      for (int p = 0; p < 8; ++p) {
        const int pt = ptg * 8 + p;
        const float x = xyx[pt], yv = xyy[pt];
        // angle pi*x*B == 2*pi*t revolutions; v_sin/v_cos take revolutions
        float tx = 0.5f * x * bx;  tx -= floorf(tx);
        float ty = 0.5f * yv * by; ty -= floorf(ty);
        const float sx = __builtin_amdgcn_sinf(tx);
        const float cx = __builtin_amdgcn_cosf(tx);
        const float sy = __builtin_amdgcn_sinf(ty);
        const float cy = __builtin_amdgcn_cosf(ty);
        const float p1 = sx * cy, p2 = cx * sy, p3 = cx * cy, p4 = sx * sy;
        const float g0 = sx, g1 = cx, g2 = sy, g3 = cy;
        const float g4 = p1 + p2, g5 = p3 - p4, g6 = p1 - p2, g7 = p3 + p4;
        uint4 wv;
        wv.x = pack2(g0, g1); wv.y = pack2(g2, g3);
        wv.z = pack2(g4, g5); wv.w = pack2(g6, g7);
        *(uint4*)(f_arena + pt * 1024 + ((fj ^ (pt & 7)) << 4)) = wv;
        psc[p] += g0 * sc8[0] + g1 * sc8[1] + g2 * sc8[2] + g3 * sc8[3]
                + g4 * sc8[4] + g5 * sc8[5] + g6 * sc8[6] + g7 * sc8[7];
        if (fj == 0) psc[p] += x * scW0 + yv * scW1;
      }
    }
    __syncthreads();

    // ---- proj GEMM (K=512): h = gelu((f@W^T + x*w0 + y*w1)*s_in + b) ----
    f32x4 acc[4][2];
#pragma unroll
    for (int a_ = 0; a_ < 4; ++a_)
#pragma unroll
      for (int b_ = 0; b_ < 2; ++b_) acc[a_][b_] = (f32x4)0.f;

    gemmK<WS, true, 16, 1024>(f_arena, wsb + PROJ_OFF(s),
                              proj_W + s * HID * INF, INF, 2,
                              lane, hq, ph, acc);

    f32x4 hres[4][2];
    {
      float xp[2], yp[2];
#pragma unroll
      for (int pf = 0; pf < 2; ++pf) {
        xp[pf] = xyx[ph * 32 + pf * 16 + ar];
        yp[pf] = xyy[ph * 32 + pf * 16 + ar];
      }
#pragma unroll
      for (int hf = 0; hf < 4; ++hf) {
        const int Hb = hq * 64 + hf * 16 + 4 * q;
        const float4 pb4 = *(const float4*)(proj_b + s * HID + Hb);
        const float pbv[4] = {pb4.x, pb4.y, pb4.z, pb4.w};
        float wx0[4], wy0[4];
#pragma unroll
        for (int r = 0; r < 4; ++r) {
          const float2 w01 = *(const float2*)(proj_W + (size_t)(s * HID + Hb + r) * INF);
          wx0[r] = w01.x; wy0[r] = w01.y;
        }
#pragma unroll
        for (int pf = 0; pf < 2; ++pf)
#pragma unroll
          for (int r = 0; r < 4; ++r)
            hres[hf][pf][r] = geluf((acc[hf][pf][r] + xp[pf] * wx0[r] + yp[pf] * wy0[r])
                                        * S_IN + pbv[r]);
      }
    }
    __syncthreads();   // all waves done reading f arena
#pragma unroll
    for (int hf = 0; hf < 4; ++hf)
#pragma unroll
      for (int pf = 0; pf < 2; ++pf)
        *(uint2*)tile_addr(h_base, hf, pf) =
            make_uint2(pack2(hres[hf][pf][0], hres[hf][pf][1]),
                       pack2(hres[hf][pf][2], hres[hf][pf][3]));
    __syncthreads();

    // ---- residual blocks ----
    for (int b = 0; b < NBLK; ++b) {
      const int wb_ = s * NBLK + b;
      f32x4 acc2[4][2];
#pragma unroll
      for (int a_ = 0; a_ < 4; ++a_)
#pragma unroll
        for (int b_ = 0; b_ < 2; ++b_) acc2[a_][b_] = (f32x4)0.f;
      gemmK<WS, false, 8, 512>(h_base, wsb + W1_OFF + wb_ * 65536,
                               blk_W1 + wb_ * 65536, HID, 0,
                               lane, hq, ph, acc2);
      // t = gelu(acc2*s_h + b1) -> t tile (region unread since post-proj barrier)
#pragma unroll
      for (int hf = 0; hf < 4; ++hf) {
        const int Hb = hq * 64 + hf * 16 + 4 * q;
        const float4 b14 = *(const float4*)(blk_b1 + wb_ * HID + Hb);
        const float b1v[4] = {b14.x, b14.y, b14.z, b14.w};
#pragma unroll
        for (int pf = 0; pf < 2; ++pf)
          *(uint2*)tile_addr(t_base, hf, pf) =
              make_uint2(pack2(geluf(acc2[hf][pf][0] * S_H + b1v[0]),
                               geluf(acc2[hf][pf][1] * S_H + b1v[1])),
                         pack2(geluf(acc2[hf][pf][2] * S_H + b1v[2]),
                               geluf(acc2[hf][pf][3] * S_H + b1v[3])));
      }
      __syncthreads();   // t complete; all GEMM1 h-reads done

      f32x4 acc3[4][2];
#pragma unroll
      for (int a_ = 0; a_ < 4; ++a_)
#pragma unroll
        for (int b_ = 0; b_ < 2; ++b_) acc3[a_][b_] = (f32x4)0.f;
      gemmK<WS, false, 8, 512>(t_base, wsb + W2_OFF + wb_ * 65536,
                               blk_W2 + wb_ * 65536, HID, 0,
                               lane, hq, ph, acc3);

      // h' = h(LDS readback, own cells) + acc3*s_h + b2
      f32x4 hn[4][2];
#pragma unroll
      for (int hf = 0; hf < 4; ++hf) {
        const int Hb = hq * 64 + hf * 16 + 4 * q;
        const float4 b24 = *(const float4*)(blk_b2 + wb_ * HID + Hb);
        const float b2v[4] = {b24.x, b24.y, b24.z, b24.w};
#pragma unroll
        for (int pf = 0; pf < 2; ++pf) {
          const uint2 u = *(const uint2*)tile_addr(h_base, hf, pf);
          hn[hf][pf][0] = __uint_as_float(u.x << 16)          + acc3[hf][pf][0] * S_H + b2v[0];
          hn[hf][pf][1] = __uint_as_float(u.x & 0xffff0000u)  + acc3[hf][pf][1] * S_H + b2v[1];
          hn[hf][pf][2] = __uint_as_float(u.y << 16)          + acc3[hf][pf][2] * S_H + b2v[2];
          hn[hf][pf][3] = __uint_as_float(u.y & 0xffff0000u)  + acc3[hf][pf][3] * S_H + b2v[3];
        }
      }
      if (b + 1 < NBLK) {
        // store h' (own cells; all GEMM1 readers passed the t barrier)
#pragma unroll
        for (int hf = 0; hf < 4; ++hf)
#pragma unroll
          for (int pf = 0; pf < 2; ++pf)
            *(uint2*)tile_addr(h_base, hf, pf) =
                make_uint2(pack2(hn[hf][pf][0], hn[hf][pf][1]),
                           pack2(hn[hf][pf][2], hn[hf][pf][3]));
      } else {
        // head partial: outl[pt] += sum_H h''[pt][H] * head_W[H]
#pragma unroll
        for (int pf = 0; pf < 2; ++pf) {
          float v = 0.f;
#pragma unroll
          for (int hf = 0; hf < 4; ++hf)
#pragma unroll
            for (int r = 0; r < 4; ++r) v += hn[hf][pf][r] * hw[hf][r];
          v += __shfl_xor(v, 16, 64);
          v += __shfl_xor(v, 32, 64);
          if (lane < 16) atomicAdd(&outl[ph * 32 + pf * 16 + ar], v);
        }
      }
      __syncthreads();
    }
  }

  // ---- shortcut reduce: psc[p] summed over 64 freq-lanes of this wave ----
#pragma unroll
  for (int p = 0; p < 8; ++p) {
    float v = psc[p];
    v += __shfl_xor(v, 1, 64);
    v += __shfl_xor(v, 2, 64);
    v += __shfl_xor(v, 4, 64);
    v += __shfl_xor(v, 8, 64);
    v += __shfl_xor(v, 16, 64);
    v += __shfl_xor(v, 32, 64);
    if (lane == 0) atomicAdd(&outl[ptg * 8 + p], v);
  }
  __syncthreads();
  if (tid < TM) out[m0 + tid] = outl[tid] + head_b[0];
}

extern "C" void kernel_launch(void* const* d_in, const int* in_sizes, int n_in,
                              void* d_out, int out_size, void* d_ws, size_t ws_size,
                              hipStream_t stream) {
  (void)in_sizes; (void)n_in;
  const float* xy     = (const float*)d_in[0];
  const float* w_x    = (const float*)d_in[1];
  const float* w_y    = (const float*)d_in[2];
  const float* proj_W = (const float*)d_in[3];
  const float* proj_b = (const float*)d_in[4];
  const float* blk_W1 = (const float*)d_in[5];
  const float* blk_b1 = (const float*)d_in[6];
  const float* blk_W2 = (const float*)d_in[7];
  const float* blk_b2 = (const float*)d_in[8];
  const float* head_W = (const float*)d_in[9];
  const float* head_b = (const float*)d_in[10];
  const float* sc_W   = (const float*)d_in[11];
  float* out = (float*)d_out;

  const bool use_ws = ws_size >= (size_t)WSB_ELEMS * 2;
  const int nblocks = out_size / TM;   // 65536/128 = 512

  if (use_ws) {
    hipFuncSetAttribute((const void*)fnet_fused<true>,
                        hipFuncAttributeMaxDynamicSharedMemorySize, SMEM_BYTES);
    cvt_weights<<<768, 256, 0, stream>>>(proj_W, blk_W1, blk_W2,
                                         (unsigned short*)d_ws);
    fnet_fused<true><<<nblocks, NTHR, SMEM_BYTES, stream>>>(
        xy, w_x, w_y, proj_W, proj_b, blk_W1, blk_b1, blk_W2, blk_b2,
        head_W, head_b, sc_W, (const unsigned short*)d_ws, out);
  } else {
    hipFuncSetAttribute((const void*)fnet_fused<false>,
                        hipFuncAttributeMaxDynamicSharedMemorySize, SMEM_BYTES);
    fnet_fused<false><<<nblocks, NTHR, SMEM_BYTES, stream>>>(
        xy, w_x, w_y, proj_W, proj_b, blk_W1, blk_b1, blk_W2, blk_b2,
        head_W, head_b, sc_W, (const unsigned short*)nullptr, out);
  }
}

// Round 6
// 616.785 us; speedup vs baseline: 2.3792x; 1.4162x over previous
//
#include <hip/hip_runtime.h>
#include <hip/hip_bf16.h>
#include <cmath>

// ---------------------------------------------------------------------------
// FourierNet fused forward, MI355X / gfx950.
// Round 6: SPILL ELIMINATION. R2-R5 all showed ~1.1-1.6 GB of HBM WRITE_SIZE
// (kernel writes 256 KB) -> scratch spill traffic. Budget at 4 waves/SIMD is
// 128 unified VGPR+AGPR; old code had 3 separate acc arrays (96 AGPR) + 32
// wb + 32 hres + persistents. Fixes:
//  - ONE acc[2][4] reused across proj/gemm1/gemm2 (zeroed between).
//  - 16 waves = 8 H-octants x 2 pt-halves (wave tile 32H x 64pt): 2 wfrag +
//    4 afrag + 8 MFMA per K-step; wb = 3-buffer rotation (24 regs) giving a
//    2-K-step weight prefetch distance (~350 cy > L2 latency).
//  - Epilogues stream hf-by-hf straight to LDS; residual base read back from
//    LDS; head weights reloaded per scale. Target <= ~110 regs, no scratch.
// Everything numeric (packing, swizzle, barriers) identical to verified R5.
// ---------------------------------------------------------------------------

#define NSC   4
#define NFREQ 64
#define HID   256
#define NBLK  2
#define INF   514
#define TM    128
#define NTHR  1024

// LDS byte offsets
#define T_OFF    65536                  // t tile (upper half of f arena)
#define XYX_OFF  131072
#define XYY_OFF  131584
#define OUTL_OFF 132096
#define SMEM_BYTES 132608

// d_ws packed-weight layout (bf16 elems): tiles of [kstep][256 rows][32 k]
#define TILE_E   8192
#define PROJ_OFF(s)    ((s) * 131072)
#define W1_OFF   524288
#define W2_OFF   1048576
#define WSB_ELEMS 1572864

static constexpr float S_IN = 0.04411042041035620f;  // 1/sqrt(514)
static constexpr float S_H  = 0.0625f;               // 1/sqrt(256)

typedef __attribute__((ext_vector_type(8))) short bf16x8;
typedef __attribute__((ext_vector_type(4))) float f32x4;

__device__ __forceinline__ unsigned short f2bf(float v) {
  __hip_bfloat16 b = __float2bfloat16(v);   // RNE
  unsigned short u;
  __builtin_memcpy(&u, &b, 2);
  return u;
}

__device__ __forceinline__ unsigned pack2(float a, float b) {
  return (unsigned)f2bf(a) | ((unsigned)f2bf(b) << 16);
}

__device__ __forceinline__ float geluf(float x) {
  return 0.5f * x * (1.0f + erff(x * 0.7071067811865476f));
}

// ---------------------------------------------------------------------------
// GEMM over KSTEPS K-steps. A (activations) from swizzled LDS, W from global.
//   W frag: row = hq*32 + hf*16 + (lane&15), k = ks*32 + 8*(lane>>4)
//   A frag: pt  = ph*64 + pf*16 + (lane&15), same k; slot16 swizzled:
//           slot' = (ks*4+q) ^ (pt&7) within a ROWB-byte row.
//   D: pt-col = lane&15, H-row = hq*32+hf*16+4*(lane>>4)+r   [m89]
// 3-buffer weight rotation -> load issued 2 K-steps before use.
// ---------------------------------------------------------------------------
template<bool WS, bool PERM, int KSTEPS, int ROWB>
__device__ __forceinline__ void gemmK(const char* a_base,
                                      const unsigned short* __restrict__ wt,
                                      const float* __restrict__ wf,
                                      const int fp_rs, const int fp_co,
                                      const int lane, const int hq, const int ph,
                                      f32x4 acc[2][4]) {
  const int ar = lane & 15;
  const int q  = lane >> 4;
  bf16x8 wb[3][2];

  auto loadw = [&](int ks, bf16x8 w[2]) {
#pragma unroll
    for (int hf = 0; hf < 2; ++hf) {
      const int row = hq * 32 + hf * 16 + ar;
      if constexpr (WS) {
        w[hf] = *(const bf16x8*)(wt + ks * TILE_E + row * 32 + q * 8);
      } else if constexpr (PERM) {
        const int j = ks * 4 + q;
        const float* p = wf + row * fp_rs + fp_co;
#pragma unroll
        for (int e = 0; e < 8; ++e) w[hf][e] = (short)f2bf(p[e * 64 + j]);
      } else {
        const float* p = wf + row * fp_rs + fp_co + ks * 32 + q * 8;
#pragma unroll
        for (int e = 0; e < 8; ++e) w[hf][e] = (short)f2bf(p[e]);
      }
    }
  };

  loadw(0, wb[0]);
  loadw(1, wb[1]);
#pragma unroll
  for (int ks = 0; ks < KSTEPS; ++ks) {
    if (ks + 2 < KSTEPS) loadw(ks + 2, wb[(ks + 2) % 3]);
    bf16x8 a[4];
#pragma unroll
    for (int pf = 0; pf < 4; ++pf) {
      const int pt = ph * 64 + pf * 16 + ar;
      const int slot = (ks * 4 + q) ^ (pt & 7);
      a[pf] = *(const bf16x8*)(a_base + pt * ROWB + (slot << 4));
    }
#pragma unroll
    for (int hf = 0; hf < 2; ++hf)
#pragma unroll
      for (int pf = 0; pf < 4; ++pf)
        acc[hf][pf] = __builtin_amdgcn_mfma_f32_16x16x32_bf16(wb[ks % 3][hf], a[pf],
                                                              acc[hf][pf], 0, 0, 0);
  }
}

// Weight pre-pack (verified R4/R5): [kstep][256][32] tiles, proj columns
// permuted k' = j*8+g (source col = 2 + g*64 + j).
__global__ void cvt_weights(const float* __restrict__ projW,
                            const float* __restrict__ w1,
                            const float* __restrict__ w2,
                            unsigned short* __restrict__ o) {
  const int tot = WSB_ELEMS;
  for (int i = blockIdx.x * blockDim.x + threadIdx.x; i < tot;
       i += gridDim.x * blockDim.x) {
    float v;
    if (i < W1_OFF) {
      const int s = i >> 17, r = i & 131071;
      const int kst = r >> 13, rr = r & 8191;
      const int h = rr >> 5, kw = rr & 31;
      const int kp = kst * 32 + kw;
      const int j = kp >> 3, g = kp & 7;
      v = projW[(s * HID + h) * INF + 2 + g * 64 + j];
    } else if (i < W2_OFF) {
      const int i2 = i - W1_OFF;
      const int w = i2 >> 16, r = i2 & 65535;
      const int kst = r >> 13, h = (r >> 5) & 255, kw = r & 31;
      v = w1[w * 65536 + h * HID + kst * 32 + kw];
    } else {
      const int i2 = i - W2_OFF;
      const int w = i2 >> 16, r = i2 & 65535;
      const int kst = r >> 13, h = (r >> 5) & 255, kw = r & 31;
      v = w2[w * 65536 + h * HID + kst * 32 + kw];
    }
    o[i] = f2bf(v);
  }
}

template<bool WS>
__global__ __launch_bounds__(NTHR, 4)
void fnet_fused(const float* __restrict__ xy,
                const float* __restrict__ w_x,
                const float* __restrict__ w_y,
                const float* __restrict__ proj_W,
                const float* __restrict__ proj_b,
                const float* __restrict__ blk_W1,
                const float* __restrict__ blk_b1,
                const float* __restrict__ blk_W2,
                const float* __restrict__ blk_b2,
                const float* __restrict__ head_W,
                const float* __restrict__ head_b,
                const float* __restrict__ sc_W,
                const unsigned short* __restrict__ wsb,
                float* __restrict__ out) {
  extern __shared__ char smem[];
  char* f_arena = smem;                  // 128 x 1024B swizzled (K=512 bf16)
  char* h_base  = smem;                  // 128 x 512B swizzled (lower half)
  char* t_base  = smem + T_OFF;          // 128 x 512B swizzled (upper half)
  float* xyx  = (float*)(smem + XYX_OFF);
  float* xyy  = (float*)(smem + XYY_OFF);
  float* outl = (float*)(smem + OUTL_OFF);

  const int tid  = threadIdx.x;
  const int lane = tid & 63;
  const int wave = tid >> 6;           // 0..15
  const int hq   = wave >> 1;          // H octant (32 H)
  const int ph   = wave & 1;           // pt half (64 pts)
  const int m0   = blockIdx.x * TM;
  const int ar   = lane & 15;
  const int q    = lane >> 4;

  if (tid < TM) {
    xyx[tid] = xy[(m0 + tid) * 2];
    xyy[tid] = xy[(m0 + tid) * 2 + 1];
    outl[tid] = 0.f;
  }

  // fourier mapping: one wave owns an 8-pt group; lane = freq j
  const int fj  = lane;        // 0..63
  const int ptg = wave;        // pts ptg*8 .. +7
  float psc[8];
#pragma unroll
  for (int p = 0; p < 8; ++p) psc[p] = 0.f;

  // swizzled h/t tile address for this lane's (hf,pf) uint2 cell
  auto tile_addr = [&](char* base, int hf, int pf) -> char* {
    const int pt = ph * 64 + pf * 16 + ar;
    const int slot = (hq * 4 + hf * 2 + (q >> 1)) ^ (pt & 7);
    return base + pt * 512 + (slot << 4) + (q & 1) * 8;
  };

  f32x4 acc[2][4];   // single accumulator, reused by all three GEMMs
  auto zacc = [&]() {
#pragma unroll
    for (int a_ = 0; a_ < 2; ++a_)
#pragma unroll
      for (int b_ = 0; b_ < 4; ++b_) acc[a_][b_] = (f32x4)0.f;
  };

  for (int s = 0; s < NSC; ++s) {
    __syncthreads();   // prev-scale LDS reads (and entry staging) complete

    // ---- fourier features -> f arena (swizzled b128 rows), shortcut dot ----
    {
      const float bx = expf(w_x[s * NFREQ + fj]);
      const float by = expf(w_y[s * NFREQ + fj]);
      float sc8[8];
#pragma unroll
      for (int g2 = 0; g2 < 8; ++g2) sc8[g2] = sc_W[s * INF + 2 + g2 * NFREQ + fj];
      const float scW0 = sc_W[s * INF], scW1 = sc_W[s * INF + 1];
#pragma unroll
      for (int p = 0; p < 8; ++p) {
        const int pt = ptg * 8 + p;
        const float x = xyx[pt], yv = xyy[pt];
        // angle pi*x*B == 2*pi*t revolutions; v_sin/v_cos take revolutions
        float tx = 0.5f * x * bx;  tx -= floorf(tx);
        float ty = 0.5f * yv * by; ty -= floorf(ty);
        const float sx = __builtin_amdgcn_sinf(tx);
        const float cx = __builtin_amdgcn_cosf(tx);
        const float sy = __builtin_amdgcn_sinf(ty);
        const float cy = __builtin_amdgcn_cosf(ty);
        const float p1 = sx * cy, p2 = cx * sy, p3 = cx * cy, p4 = sx * sy;
        const float g0 = sx, g1 = cx, g2 = sy, g3 = cy;
        const float g4 = p1 + p2, g5 = p3 - p4, g6 = p1 - p2, g7 = p3 + p4;
        uint4 wv;
        wv.x = pack2(g0, g1); wv.y = pack2(g2, g3);
        wv.z = pack2(g4, g5); wv.w = pack2(g6, g7);
        *(uint4*)(f_arena + pt * 1024 + ((fj ^ (pt & 7)) << 4)) = wv;
        psc[p] += g0 * sc8[0] + g1 * sc8[1] + g2 * sc8[2] + g3 * sc8[3]
                + g4 * sc8[4] + g5 * sc8[5] + g6 * sc8[6] + g7 * sc8[7];
        if (fj == 0) psc[p] += x * scW0 + yv * scW1;
      }
    }
    __syncthreads();

    // ---- proj GEMM (K=512): h = gelu((f@W^T + x*w0 + y*w1)*s_in + b) ----
    zacc();
    gemmK<WS, true, 16, 1024>(f_arena, wsb + PROJ_OFF(s),
                              proj_W + s * HID * INF, INF, 2,
                              lane, hq, ph, acc);
    __syncthreads();   // all waves done reading f arena

    // epilogue streamed hf-by-hf, straight to LDS h tile
#pragma unroll
    for (int hf = 0; hf < 2; ++hf) {
      const int Hb = hq * 32 + hf * 16 + 4 * q;
      const float4 pb4 = *(const float4*)(proj_b + s * HID + Hb);
      const float pbv[4] = {pb4.x, pb4.y, pb4.z, pb4.w};
      float wx0[4], wy0[4];
#pragma unroll
      for (int r = 0; r < 4; ++r) {
        const float2 w01 = *(const float2*)(proj_W + (size_t)(s * HID + Hb + r) * INF);
        wx0[r] = w01.x; wy0[r] = w01.y;
      }
#pragma unroll
      for (int pf = 0; pf < 4; ++pf) {
        const int pt = ph * 64 + pf * 16 + ar;
        const float xp = xyx[pt], yp = xyy[pt];
        float hv[4];
#pragma unroll
        for (int r = 0; r < 4; ++r)
          hv[r] = geluf((acc[hf][pf][r] + xp * wx0[r] + yp * wy0[r]) * S_IN + pbv[r]);
        *(uint2*)tile_addr(h_base, hf, pf) =
            make_uint2(pack2(hv[0], hv[1]), pack2(hv[2], hv[3]));
      }
    }
    __syncthreads();

    // ---- residual blocks ----
    for (int b = 0; b < NBLK; ++b) {
      const int wb_ = s * NBLK + b;
      zacc();
      gemmK<WS, false, 8, 512>(h_base, wsb + W1_OFF + wb_ * 65536,
                               blk_W1 + wb_ * 65536, HID, 0,
                               lane, hq, ph, acc);
      // t = gelu(acc*s_h + b1) -> t tile (region unread since last barrier)
#pragma unroll
      for (int hf = 0; hf < 2; ++hf) {
        const int Hb = hq * 32 + hf * 16 + 4 * q;
        const float4 b14 = *(const float4*)(blk_b1 + wb_ * HID + Hb);
        const float b1v[4] = {b14.x, b14.y, b14.z, b14.w};
#pragma unroll
        for (int pf = 0; pf < 4; ++pf)
          *(uint2*)tile_addr(t_base, hf, pf) =
              make_uint2(pack2(geluf(acc[hf][pf][0] * S_H + b1v[0]),
                               geluf(acc[hf][pf][1] * S_H + b1v[1])),
                         pack2(geluf(acc[hf][pf][2] * S_H + b1v[2]),
                               geluf(acc[hf][pf][3] * S_H + b1v[3])));
      }
      __syncthreads();   // t complete; all GEMM1 h-reads done

      zacc();
      gemmK<WS, false, 8, 512>(t_base, wsb + W2_OFF + wb_ * 65536,
                               blk_W2 + wb_ * 65536, HID, 0,
                               lane, hq, ph, acc);

      if (b + 1 < NBLK) {
        // h' = h(LDS readback) + acc*s_h + b2 -> back to h tile (own cells;
        // all GEMM readers passed the pre-GEMM2 barrier)
#pragma unroll
        for (int hf = 0; hf < 2; ++hf) {
          const int Hb = hq * 32 + hf * 16 + 4 * q;
          const float4 b24 = *(const float4*)(blk_b2 + wb_ * HID + Hb);
          const float b2v[4] = {b24.x, b24.y, b24.z, b24.w};
#pragma unroll
          for (int pf = 0; pf < 4; ++pf) {
            const uint2 u = *(const uint2*)tile_addr(h_base, hf, pf);
            float hv[4];
            hv[0] = __uint_as_float(u.x << 16)         + acc[hf][pf][0] * S_H + b2v[0];
            hv[1] = __uint_as_float(u.x & 0xffff0000u) + acc[hf][pf][1] * S_H + b2v[1];
            hv[2] = __uint_as_float(u.y << 16)         + acc[hf][pf][2] * S_H + b2v[2];
            hv[3] = __uint_as_float(u.y & 0xffff0000u) + acc[hf][pf][3] * S_H + b2v[3];
            *(uint2*)tile_addr(h_base, hf, pf) =
                make_uint2(pack2(hv[0], hv[1]), pack2(hv[2], hv[3]));
          }
        }
      } else {
        // final: head partial outl[pt] += sum_H h''[pt][H] * head_W[H]
#pragma unroll
        for (int pf = 0; pf < 4; ++pf) {
          float v = 0.f;
#pragma unroll
          for (int hf = 0; hf < 2; ++hf) {
            const int Hb = hq * 32 + hf * 16 + 4 * q;
            const float4 b24 = *(const float4*)(blk_b2 + wb_ * HID + Hb);
            const float4 hw4 = *(const float4*)(head_W + Hb);
            const uint2 u = *(const uint2*)tile_addr(h_base, hf, pf);
            const float b2v[4] = {b24.x, b24.y, b24.z, b24.w};
            const float hwv[4] = {hw4.x, hw4.y, hw4.z, hw4.w};
            const float hb0 = __uint_as_float(u.x << 16);
            const float hb1 = __uint_as_float(u.x & 0xffff0000u);
            const float hb2 = __uint_as_float(u.y << 16);
            const float hb3 = __uint_as_float(u.y & 0xffff0000u);
            v += (hb0 + acc[hf][pf][0] * S_H + b2v[0]) * hwv[0]
               + (hb1 + acc[hf][pf][1] * S_H + b2v[1]) * hwv[1]
               + (hb2 + acc[hf][pf][2] * S_H + b2v[2]) * hwv[2]
               + (hb3 + acc[hf][pf][3] * S_H + b2v[3]) * hwv[3];
          }
          v += __shfl_xor(v, 16, 64);
          v += __shfl_xor(v, 32, 64);
          if (lane < 16) atomicAdd(&outl[ph * 64 + pf * 16 + ar], v);
        }
      }
      __syncthreads();
    }
  }

  // ---- shortcut reduce: psc[p] summed over 64 freq-lanes of this wave ----
#pragma unroll
  for (int p = 0; p < 8; ++p) {
    float v = psc[p];
    v += __shfl_xor(v, 1, 64);
    v += __shfl_xor(v, 2, 64);
    v += __shfl_xor(v, 4, 64);
    v += __shfl_xor(v, 8, 64);
    v += __shfl_xor(v, 16, 64);
    v += __shfl_xor(v, 32, 64);
    if (lane == 0) atomicAdd(&outl[ptg * 8 + p], v);
  }
  __syncthreads();
  if (tid < TM) out[m0 + tid] = outl[tid] + head_b[0];
}

extern "C" void kernel_launch(void* const* d_in, const int* in_sizes, int n_in,
                              void* d_out, int out_size, void* d_ws, size_t ws_size,
                              hipStream_t stream) {
  (void)in_sizes; (void)n_in;
  const float* xy     = (const float*)d_in[0];
  const float* w_x    = (const float*)d_in[1];
  const float* w_y    = (const float*)d_in[2];
  const float* proj_W = (const float*)d_in[3];
  const float* proj_b = (const float*)d_in[4];
  const float* blk_W1 = (const float*)d_in[5];
  const float* blk_b1 = (const float*)d_in[6];
  const float* blk_W2 = (const float*)d_in[7];
  const float* blk_b2 = (const float*)d_in[8];
  const float* head_W = (const float*)d_in[9];
  const float* head_b = (const float*)d_in[10];
  const float* sc_W   = (const float*)d_in[11];
  float* out = (float*)d_out;

  const bool use_ws = ws_size >= (size_t)WSB_ELEMS * 2;
  const int nblocks = out_size / TM;   // 65536/128 = 512

  if (use_ws) {
    hipFuncSetAttribute((const void*)fnet_fused<true>,
                        hipFuncAttributeMaxDynamicSharedMemorySize, SMEM_BYTES);
    cvt_weights<<<768, 256, 0, stream>>>(proj_W, blk_W1, blk_W2,
                                         (unsigned short*)d_ws);
    fnet_fused<true><<<nblocks, NTHR, SMEM_BYTES, stream>>>(
        xy, w_x, w_y, proj_W, proj_b, blk_W1, blk_b1, blk_W2, blk_b2,
        head_W, head_b, sc_W, (const unsigned short*)d_ws, out);
  } else {
    hipFuncSetAttribute((const void*)fnet_fused<false>,
                        hipFuncAttributeMaxDynamicSharedMemorySize, SMEM_BYTES);
    fnet_fused<false><<<nblocks, NTHR, SMEM_BYTES, stream>>>(
        xy, w_x, w_y, proj_W, proj_b, blk_W1, blk_b1, blk_W2, blk_b2,
        head_W, head_b, sc_W, (const unsigned short*)nullptr, out);
  }
}

// Round 8
// 477.741 us; speedup vs baseline: 3.0716x; 1.2910x over previous
//
#include <hip/hip_runtime.h>
#include <hip/hip_bf16.h>
#include <cmath>

// ---------------------------------------------------------------------------
// FourierNet fused forward, MI355X / gfx950.
// Round 8: fix R7's LDS overlap bug. h tile is 64 KB (128 pts x 256 H x 2B),
// so t must sit at +65536, not +32768 (R7 clobbered h rows 64..127 with
// t rows 0..63 -> absmax 4.83). Single-line fix; all else identical to R7:
//  - 512 thr / 8 waves (2/SIMD), launch_bounds(512,2) -> 256-reg budget,
//    zero spills (acc 64 + wb 48 + a 16 + addr ~ 150 < 256).
//  - 8 waves = 4 H-quarters x 2 pt-halves; per K-step 4 wfrag + 4 afrag +
//    16 MFMA; 3-buffer weight prefetch from L2-resident packed set.
//  - TM=128, K=512 f-arena swizzled in LDS; h at 0, t at 64K (both alias f
//    across the post-proj barrier). 1 block/CU.
// ---------------------------------------------------------------------------

#define NSC   4
#define NFREQ 64
#define HID   256
#define NBLK  2
#define INF   514
#define TM    128
#define NTHR  512

// LDS byte offsets
#define T_OFF    65536                  // t tile (second 64 KB of f arena)
#define XYX_OFF  131072
#define XYY_OFF  131584
#define OUTL_OFF 132096
#define SMEM_BYTES 132608

// d_ws packed-weight layout (bf16 elems): tiles of [kstep][256 rows][32 k]
#define TILE_E   8192
#define PROJ_OFF(s)    ((s) * 131072)
#define W1_OFF   524288
#define W2_OFF   1048576
#define WSB_ELEMS 1572864

static constexpr float S_IN = 0.04411042041035620f;  // 1/sqrt(514)
static constexpr float S_H  = 0.0625f;               // 1/sqrt(256)

typedef __attribute__((ext_vector_type(8))) short bf16x8;
typedef __attribute__((ext_vector_type(4))) float f32x4;

__device__ __forceinline__ unsigned short f2bf(float v) {
  __hip_bfloat16 b = __float2bfloat16(v);   // RNE
  unsigned short u;
  __builtin_memcpy(&u, &b, 2);
  return u;
}

__device__ __forceinline__ unsigned pack2(float a, float b) {
  return (unsigned)f2bf(a) | ((unsigned)f2bf(b) << 16);
}

__device__ __forceinline__ float geluf(float x) {
  return 0.5f * x * (1.0f + erff(x * 0.7071067811865476f));
}

// ---------------------------------------------------------------------------
// GEMM over KSTEPS K-steps. A from swizzled LDS, W from global (packed).
//   W frag: row = hq*64 + hf*16 + (lane&15), k = ks*32 + 8*(lane>>4)
//   A frag: pt  = ph*64 + pf*16 + (lane&15), same k; slot16 swizzled:
//           slot' = (ks*4+q) ^ (pt&7) within a ROWB-byte row.
//   D: pt-col = lane&15, H-row = hq*64+hf*16+4*(lane>>4)+r   [m89]
// 3-buffer weight rotation -> load issued 2 K-steps (~310 cy) before use.
// ---------------------------------------------------------------------------
template<bool WS, bool PERM, int KSTEPS, int ROWB>
__device__ __forceinline__ void gemmK(const char* a_base,
                                      const unsigned short* __restrict__ wt,
                                      const float* __restrict__ wf,
                                      const int fp_rs, const int fp_co,
                                      const int lane, const int hq, const int ph,
                                      f32x4 acc[4][4]) {
  const int ar = lane & 15;
  const int q  = lane >> 4;
  bf16x8 wb[3][4];

  auto loadw = [&](int ks, bf16x8 w[4]) {
#pragma unroll
    for (int hf = 0; hf < 4; ++hf) {
      const int row = hq * 64 + hf * 16 + ar;
      if constexpr (WS) {
        w[hf] = *(const bf16x8*)(wt + ks * TILE_E + row * 32 + q * 8);
      } else if constexpr (PERM) {
        const int j = ks * 4 + q;
        const float* p = wf + row * fp_rs + fp_co;
#pragma unroll
        for (int e = 0; e < 8; ++e) w[hf][e] = (short)f2bf(p[e * 64 + j]);
      } else {
        const float* p = wf + row * fp_rs + fp_co + ks * 32 + q * 8;
#pragma unroll
        for (int e = 0; e < 8; ++e) w[hf][e] = (short)f2bf(p[e]);
      }
    }
  };

  loadw(0, wb[0]);
  loadw(1, wb[1]);
#pragma unroll
  for (int ks = 0; ks < KSTEPS; ++ks) {
    if (ks + 2 < KSTEPS) loadw(ks + 2, wb[(ks + 2) % 3]);
    bf16x8 a[4];
#pragma unroll
    for (int pf = 0; pf < 4; ++pf) {
      const int pt = ph * 64 + pf * 16 + ar;
      const int slot = (ks * 4 + q) ^ (pt & 7);
      a[pf] = *(const bf16x8*)(a_base + pt * ROWB + (slot << 4));
    }
#pragma unroll
    for (int hf = 0; hf < 4; ++hf)
#pragma unroll
      for (int pf = 0; pf < 4; ++pf)
        acc[hf][pf] = __builtin_amdgcn_mfma_f32_16x16x32_bf16(wb[ks % 3][hf], a[pf],
                                                              acc[hf][pf], 0, 0, 0);
  }
}

// Weight pre-pack (verified R4-R6): [kstep][256][32] tiles, proj columns
// permuted k' = j*8+g (source col = 2 + g*64 + j).
__global__ void cvt_weights(const float* __restrict__ projW,
                            const float* __restrict__ w1,
                            const float* __restrict__ w2,
                            unsigned short* __restrict__ o) {
  const int tot = WSB_ELEMS;
  for (int i = blockIdx.x * blockDim.x + threadIdx.x; i < tot;
       i += gridDim.x * blockDim.x) {
    float v;
    if (i < W1_OFF) {
      const int s = i >> 17, r = i & 131071;
      const int kst = r >> 13, rr = r & 8191;
      const int h = rr >> 5, kw = rr & 31;
      const int kp = kst * 32 + kw;
      const int j = kp >> 3, g = kp & 7;
      v = projW[(s * HID + h) * INF + 2 + g * 64 + j];
    } else if (i < W2_OFF) {
      const int i2 = i - W1_OFF;
      const int w = i2 >> 16, r = i2 & 65535;
      const int kst = r >> 13, h = (r >> 5) & 255, kw = r & 31;
      v = w1[w * 65536 + h * HID + kst * 32 + kw];
    } else {
      const int i2 = i - W2_OFF;
      const int w = i2 >> 16, r = i2 & 65535;
      const int kst = r >> 13, h = (r >> 5) & 255, kw = r & 31;
      v = w2[w * 65536 + h * HID + kst * 32 + kw];
    }
    o[i] = f2bf(v);
  }
}

template<bool WS>
__global__ __launch_bounds__(NTHR, 2)
void fnet_fused(const float* __restrict__ xy,
                const float* __restrict__ w_x,
                const float* __restrict__ w_y,
                const float* __restrict__ proj_W,
                const float* __restrict__ proj_b,
                const float* __restrict__ blk_W1,
                const float* __restrict__ blk_b1,
                const float* __restrict__ blk_W2,
                const float* __restrict__ blk_b2,
                const float* __restrict__ head_W,
                const float* __restrict__ head_b,
                const float* __restrict__ sc_W,
                const unsigned short* __restrict__ wsb,
                float* __restrict__ out) {
  extern __shared__ char smem[];
  char* f_arena = smem;                  // 128 x 1024B swizzled (K=512 bf16)
  char* h_base  = smem;                  // 128 x 512B swizzled (bytes 0..64K)
  char* t_base  = smem + T_OFF;          // 128 x 512B swizzled (64K..128K)
  float* xyx  = (float*)(smem + XYX_OFF);
  float* xyy  = (float*)(smem + XYY_OFF);
  float* outl = (float*)(smem + OUTL_OFF);

  const int tid  = threadIdx.x;
  const int lane = tid & 63;
  const int wave = tid >> 6;           // 0..7
  const int hq   = wave >> 1;          // H quarter (64 H)
  const int ph   = wave & 1;           // pt half (64 pts)
  const int m0   = blockIdx.x * TM;
  const int ar   = lane & 15;
  const int q    = lane >> 4;

  if (tid < TM) {
    xyx[tid] = xy[(m0 + tid) * 2];
    xyy[tid] = xy[(m0 + tid) * 2 + 1];
    outl[tid] = 0.f;
  }

  // swizzled h/t tile address for this lane's (hf,pf) uint2 cell
  auto tile_addr = [&](char* base, int hf, int pf) -> char* {
    const int pt = ph * 64 + pf * 16 + ar;
    const int slot = (hq * 8 + hf * 2 + (q >> 1)) ^ (pt & 7);
    return base + pt * 512 + (slot << 4) + (q & 1) * 8;
  };

  f32x4 acc[4][4];   // single accumulator, reused by all three GEMMs
  auto zacc = [&]() {
#pragma unroll
    for (int a_ = 0; a_ < 4; ++a_)
#pragma unroll
      for (int b_ = 0; b_ < 4; ++b_) acc[a_][b_] = (f32x4)0.f;
  };

  for (int s = 0; s < NSC; ++s) {
    __syncthreads();   // prev-scale LDS reads (and entry staging) complete

    // ---- fourier features -> f arena; shortcut dot -> outl atomics ----
    // wave owns 16 pts; lane = freq j (0..63)
    {
      const int fj = lane;
      const float bx = expf(w_x[s * NFREQ + fj]);
      const float by = expf(w_y[s * NFREQ + fj]);
      float sc8[8];
#pragma unroll
      for (int g2 = 0; g2 < 8; ++g2) sc8[g2] = sc_W[s * INF + 2 + g2 * NFREQ + fj];
      const float scW0 = sc_W[s * INF], scW1 = sc_W[s * INF + 1];
#pragma unroll
      for (int p = 0; p < 16; ++p) {
        const int pt = wave * 16 + p;
        const float x = xyx[pt], yv = xyy[pt];
        // angle pi*x*B == 2*pi*t revolutions; v_sin/v_cos take revolutions
        float tx = 0.5f * x * bx;  tx -= floorf(tx);
        float ty = 0.5f * yv * by; ty -= floorf(ty);
        const float sx = __builtin_amdgcn_sinf(tx);
        const float cx = __builtin_amdgcn_cosf(tx);
        const float sy = __builtin_amdgcn_sinf(ty);
        const float cy = __builtin_amdgcn_cosf(ty);
        const float p1 = sx * cy, p2 = cx * sy, p3 = cx * cy, p4 = sx * sy;
        const float g0 = sx, g1 = cx, g2 = sy, g3 = cy;
        const float g4 = p1 + p2, g5 = p3 - p4, g6 = p1 - p2, g7 = p3 + p4;
        uint4 wv;
        wv.x = pack2(g0, g1); wv.y = pack2(g2, g3);
        wv.z = pack2(g4, g5); wv.w = pack2(g6, g7);
        *(uint4*)(f_arena + pt * 1024 + ((fj ^ (pt & 7)) << 4)) = wv;
        float psum = g0 * sc8[0] + g1 * sc8[1] + g2 * sc8[2] + g3 * sc8[3]
                   + g4 * sc8[4] + g5 * sc8[5] + g6 * sc8[6] + g7 * sc8[7];
        psum += __shfl_xor(psum, 1, 64);
        psum += __shfl_xor(psum, 2, 64);
        psum += __shfl_xor(psum, 4, 64);
        psum += __shfl_xor(psum, 8, 64);
        psum += __shfl_xor(psum, 16, 64);
        psum += __shfl_xor(psum, 32, 64);
        if (lane == 0) atomicAdd(&outl[pt], psum + x * scW0 + yv * scW1);
      }
    }
    __syncthreads();

    // ---- proj GEMM (K=512): h = gelu((f@W^T + x*w0 + y*w1)*s_in + b) ----
    zacc();
    gemmK<WS, true, 16, 1024>(f_arena, wsb + PROJ_OFF(s),
                              proj_W + s * HID * INF, INF, 2,
                              lane, hq, ph, acc);
    __syncthreads();   // all waves done reading f arena

    // epilogue streamed hf-by-hf, straight to LDS h tile
#pragma unroll
    for (int hf = 0; hf < 4; ++hf) {
      const int Hb = hq * 64 + hf * 16 + 4 * q;
      const float4 pb4 = *(const float4*)(proj_b + s * HID + Hb);
      const float pbv[4] = {pb4.x, pb4.y, pb4.z, pb4.w};
      float wx0[4], wy0[4];
#pragma unroll
      for (int r = 0; r < 4; ++r) {
        const float2 w01 = *(const float2*)(proj_W + (size_t)(s * HID + Hb + r) * INF);
        wx0[r] = w01.x; wy0[r] = w01.y;
      }
#pragma unroll
      for (int pf = 0; pf < 4; ++pf) {
        const int pt = ph * 64 + pf * 16 + ar;
        const float xp = xyx[pt], yp = xyy[pt];
        float hv[4];
#pragma unroll
        for (int r = 0; r < 4; ++r)
          hv[r] = geluf((acc[hf][pf][r] + xp * wx0[r] + yp * wy0[r]) * S_IN + pbv[r]);
        *(uint2*)tile_addr(h_base, hf, pf) =
            make_uint2(pack2(hv[0], hv[1]), pack2(hv[2], hv[3]));
      }
    }
    __syncthreads();

    // ---- residual blocks ----
    for (int b = 0; b < NBLK; ++b) {
      const int wb_ = s * NBLK + b;
      zacc();
      gemmK<WS, false, 8, 512>(h_base, wsb + W1_OFF + wb_ * 65536,
                               blk_W1 + wb_ * 65536, HID, 0,
                               lane, hq, ph, acc);
      // t = gelu(acc*s_h + b1) -> t tile (disjoint from h; gemm1 may still run)
#pragma unroll
      for (int hf = 0; hf < 4; ++hf) {
        const int Hb = hq * 64 + hf * 16 + 4 * q;
        const float4 b14 = *(const float4*)(blk_b1 + wb_ * HID + Hb);
        const float b1v[4] = {b14.x, b14.y, b14.z, b14.w};
#pragma unroll
        for (int pf = 0; pf < 4; ++pf)
          *(uint2*)tile_addr(t_base, hf, pf) =
              make_uint2(pack2(geluf(acc[hf][pf][0] * S_H + b1v[0]),
                               geluf(acc[hf][pf][1] * S_H + b1v[1])),
                         pack2(geluf(acc[hf][pf][2] * S_H + b1v[2]),
                               geluf(acc[hf][pf][3] * S_H + b1v[3])));
      }
      __syncthreads();   // t complete; all GEMM1 h-reads done

      zacc();
      gemmK<WS, false, 8, 512>(t_base, wsb + W2_OFF + wb_ * 65536,
                               blk_W2 + wb_ * 65536, HID, 0,
                               lane, hq, ph, acc);

      if (b + 1 < NBLK) {
        // h' = h(LDS readback, own cells) + acc*s_h + b2 -> h tile
#pragma unroll
        for (int hf = 0; hf < 4; ++hf) {
          const int Hb = hq * 64 + hf * 16 + 4 * q;
          const float4 b24 = *(const float4*)(blk_b2 + wb_ * HID + Hb);
          const float b2v[4] = {b24.x, b24.y, b24.z, b24.w};
#pragma unroll
          for (int pf = 0; pf < 4; ++pf) {
            const uint2 u = *(const uint2*)tile_addr(h_base, hf, pf);
            float hv[4];
            hv[0] = __uint_as_float(u.x << 16)         + acc[hf][pf][0] * S_H + b2v[0];
            hv[1] = __uint_as_float(u.x & 0xffff0000u) + acc[hf][pf][1] * S_H + b2v[1];
            hv[2] = __uint_as_float(u.y << 16)         + acc[hf][pf][2] * S_H + b2v[2];
            hv[3] = __uint_as_float(u.y & 0xffff0000u) + acc[hf][pf][3] * S_H + b2v[3];
            *(uint2*)tile_addr(h_base, hf, pf) =
                make_uint2(pack2(hv[0], hv[1]), pack2(hv[2], hv[3]));
          }
        }
      } else {
        // final: head partial outl[pt] += sum_H h''[pt][H] * head_W[H]
#pragma unroll
        for (int pf = 0; pf < 4; ++pf) {
          float v = 0.f;
#pragma unroll
          for (int hf = 0; hf < 4; ++hf) {
            const int Hb = hq * 64 + hf * 16 + 4 * q;
            const float4 b24 = *(const float4*)(blk_b2 + wb_ * HID + Hb);
            const float4 hw4 = *(const float4*)(head_W + Hb);
            const uint2 u = *(const uint2*)tile_addr(h_base, hf, pf);
            const float b2v[4] = {b24.x, b24.y, b24.z, b24.w};
            const float hwv[4] = {hw4.x, hw4.y, hw4.z, hw4.w};
            v += (__uint_as_float(u.x << 16)         + acc[hf][pf][0] * S_H + b2v[0]) * hwv[0]
               + (__uint_as_float(u.x & 0xffff0000u) + acc[hf][pf][1] * S_H + b2v[1]) * hwv[1]
               + (__uint_as_float(u.y << 16)         + acc[hf][pf][2] * S_H + b2v[2]) * hwv[2]
               + (__uint_as_float(u.y & 0xffff0000u) + acc[hf][pf][3] * S_H + b2v[3]) * hwv[3];
          }
          v += __shfl_xor(v, 16, 64);
          v += __shfl_xor(v, 32, 64);
          if (lane < 16) atomicAdd(&outl[ph * 64 + pf * 16 + ar], v);
        }
      }
      __syncthreads();
    }
  }

  if (tid < TM) out[m0 + tid] = outl[tid] + head_b[0];
}

extern "C" void kernel_launch(void* const* d_in, const int* in_sizes, int n_in,
                              void* d_out, int out_size, void* d_ws, size_t ws_size,
                              hipStream_t stream) {
  (void)in_sizes; (void)n_in;
  const float* xy     = (const float*)d_in[0];
  const float* w_x    = (const float*)d_in[1];
  const float* w_y    = (const float*)d_in[2];
  const float* proj_W = (const float*)d_in[3];
  const float* proj_b = (const float*)d_in[4];
  const float* blk_W1 = (const float*)d_in[5];
  const float* blk_b1 = (const float*)d_in[6];
  const float* blk_W2 = (const float*)d_in[7];
  const float* blk_b2 = (const float*)d_in[8];
  const float* head_W = (const float*)d_in[9];
  const float* head_b = (const float*)d_in[10];
  const float* sc_W   = (const float*)d_in[11];
  float* out = (float*)d_out;

  const bool use_ws = ws_size >= (size_t)WSB_ELEMS * 2;
  const int nblocks = out_size / TM;   // 65536/128 = 512

  if (use_ws) {
    hipFuncSetAttribute((const void*)fnet_fused<true>,
                        hipFuncAttributeMaxDynamicSharedMemorySize, SMEM_BYTES);
    cvt_weights<<<768, 256, 0, stream>>>(proj_W, blk_W1, blk_W2,
                                         (unsigned short*)d_ws);
    fnet_fused<true><<<nblocks, NTHR, SMEM_BYTES, stream>>>(
        xy, w_x, w_y, proj_W, proj_b, blk_W1, blk_b1, blk_W2, blk_b2,
        head_W, head_b, sc_W, (const unsigned short*)d_ws, out);
  } else {
    hipFuncSetAttribute((const void*)fnet_fused<false>,
                        hipFuncAttributeMaxDynamicSharedMemorySize, SMEM_BYTES);
    fnet_fused<false><<<nblocks, NTHR, SMEM_BYTES, stream>>>(
        xy, w_x, w_y, proj_W, proj_b, blk_W1, blk_b1, blk_W2, blk_b2,
        head_W, head_b, sc_W, (const unsigned short*)nullptr, out);
  }
}